// Round 5
// baseline (242.339 us; speedup 1.0000x reference)
//
#include <hip/hip_runtime.h>

typedef __attribute__((ext_vector_type(8))) __bf16 bf16x8;
typedef __attribute__((ext_vector_type(4))) float f32x4;
typedef __attribute__((ext_vector_type(16))) float f32x16;
typedef unsigned short u16;
typedef unsigned int u32;

#define MFMA16(a, b, c) __builtin_amdgcn_mfma_f32_16x16x32_bf16((a), (b), (c), 0, 0, 0)
#define MFMA32(a, b, c) __builtin_amdgcn_mfma_f32_32x32x16_bf16((a), (b), (c), 0, 0, 0)

__device__ __forceinline__ u16 f2bf(float f) {
  return (u16)((__float_as_uint(f) + 0x8000u) >> 16);
}

// dims
#define BDIM 2
#define SDIM 2048
#define EDIM 1024
#define HDIM 16
#define HD 64
#define MDIM (BDIM * SDIM)  // 4096

// q pre-scale: 0.125 * log2(e), folded into q at the QKV-GEMM epilogue
#define SC_C1 0.1803368801111355f

typedef __attribute__((address_space(3))) void lds_void;
typedef __attribute__((address_space(1))) void g_void;

__device__ __forceinline__ void async_lds16(const void* g, void* lds_byte) {
  __builtin_amdgcn_global_load_lds((const g_void*)g, (lds_void*)lds_byte, 16, 0, 0);
}

// ===================== cvt3: three f32 -> bf16 arrays, one launch ==========
__global__ __launch_bounds__(256) void cvt3_kernel(
    const float* __restrict__ s0, u16* __restrict__ d0, int n0,
    const float* __restrict__ s1, u16* __restrict__ d1, int n1,
    const float* __restrict__ s2, u16* __restrict__ d2, int n2) {
  int i = (blockIdx.x * 256 + threadIdx.x) * 8;
  const float* s;
  u16* d;
  if (i < n0) {
    s = s0 + i; d = d0 + i;
  } else if (i < n0 + n1) {
    s = s1 + (i - n0); d = d1 + (i - n0);
  } else if (i < n0 + n1 + n2) {
    s = s2 + (i - n0 - n1); d = d2 + (i - n0 - n1);
  } else {
    return;
  }
  float4 f0 = *(const float4*)(s);
  float4 f1 = *(const float4*)(s + 4);
  union { uint4 u; u16 h[8]; } o;
  o.h[0] = f2bf(f0.x); o.h[1] = f2bf(f0.y); o.h[2] = f2bf(f0.z); o.h[3] = f2bf(f0.w);
  o.h[4] = f2bf(f1.x); o.h[5] = f2bf(f1.y); o.h[6] = f2bf(f1.z); o.h[7] = f2bf(f1.w);
  *(uint4*)(d) = o.u;
}

// ===================== GEMM1: QKV projection (128x128 tile, BK=64) ====
// out: q bf16 [B][H][S][HD] PRE-SCALED by SC_C1; k bf16 [B][H][S][HD];
//      v bf16 TRANSPOSED [B][H][HD][S]
__global__ __launch_bounds__(256) void gemm_qkv_kernel(
    const u16* __restrict__ X, const u16* __restrict__ W,
    const float* __restrict__ bias, u16* __restrict__ qb,
    u16* __restrict__ kb, u16* __restrict__ vtb) {
  __shared__ __align__(16) u16 As[128 * 64];
  __shared__ __align__(16) u16 Bs[128 * 64];
  const int m0 = blockIdx.x * 128, n0 = blockIdx.y * 128;
  const bool isV = (n0 >= 2 * EDIM);
  const int t = threadIdx.x;
  const int l = t & 63;
  const int quad = l >> 4, col = l & 15;
  const int wid = t >> 6;
  const int mh = wid & 1, nh = wid >> 1;
  const int wofs = (t & 192) << 4;  // wave_id * 1024 bytes
  f32x4 acc[4][4] = {};
  const u16* Ab = X + (size_t)m0 * EDIM;
  const u16* Bb = W + (size_t)n0 * EDIM;
  char* AsB = (char*)As;
  char* BsB = (char*)Bs;

  for (int k0 = 0; k0 < EDIM; k0 += 64) {
    __syncthreads();
#pragma unroll
    for (int p = 0; p < 4; p++) {
      int idx = p * 256 + t;       // 0..1023
      int row = idx >> 3;          // 0..127
      int gch = (idx & 7) ^ (row & 7);
      async_lds16(Ab + (size_t)row * EDIM + k0 + gch * 8, AsB + p * 4096 + wofs);
      async_lds16(Bb + (size_t)row * EDIM + k0 + gch * 8, BsB + p * 4096 + wofs);
    }
    __syncthreads();
#pragma unroll
    for (int kk = 0; kk < 2; kk++) {
      bf16x8 af[4], bfr[4];
#pragma unroll
      for (int i = 0; i < 4; i++) {
        int ra = 64 * mh + 16 * i + col;
        af[i] = *(const bf16x8*)&As[ra * 64 + (((kk * 4 + quad) ^ (ra & 7)) * 8)];
        int rb = 64 * nh + 16 * i + col;
        bfr[i] = *(const bf16x8*)&Bs[rb * 64 + (((kk * 4 + quad) ^ (rb & 7)) * 8)];
      }
      if (isV) {
#pragma unroll
        for (int i = 0; i < 4; i++)
#pragma unroll
          for (int j = 0; j < 4; j++)
            acc[i][j] = MFMA16(bfr[i], af[j], acc[i][j]);  // rows = W features
      } else {
#pragma unroll
        for (int i = 0; i < 4; i++)
#pragma unroll
          for (int j = 0; j < 4; j++)
            acc[i][j] = MFMA16(af[i], bfr[j], acc[i][j]);  // rows = tokens
      }
    }
  }

  if (isV) {
#pragma unroll
    for (int i = 0; i < 4; i++)
#pragma unroll
      for (int j = 0; j < 4; j++)
#pragma unroll
        for (int r = 0; r < 4; r++) {
          int n = n0 + 64 * nh + 16 * i + quad * 4 + r;  // feature (2048..3071)
          int m = m0 + 64 * mh + 16 * j + col;           // token
          float val = acc[i][j][r] + bias[n];
          int e = n & 1023;
          int hh = e >> 6, d = e & 63;
          int bb = m >> 11, s = m & 2047;
          vtb[(((size_t)(bb * HDIM + hh)) * HD + d) * SDIM + s] = f2bf(val);
        }
  } else {
    const float qscale = (n0 < EDIM) ? SC_C1 : 1.0f;  // block-uniform
#pragma unroll
    for (int i = 0; i < 4; i++)
#pragma unroll
      for (int j = 0; j < 4; j++)
#pragma unroll
        for (int r = 0; r < 4; r++) {
          int m = m0 + 64 * mh + 16 * i + quad * 4 + r;
          int n = n0 + 64 * nh + 16 * j + col;
          float val = (acc[i][j][r] + bias[n]) * qscale;
          int which = n >> 10, e = n & 1023;
          int hh = e >> 6, d = e & 63;
          int bb = m >> 11, s = m & 2047;
          u16* dst = (which == 0) ? qb : kb;
          dst[(((size_t)(bb * HDIM + hh)) * SDIM + s) * HD + d] = f2bf(val);
        }
  }
}

// ===================== Attention: k-split wave pairs, 4 blocks/CU ==========
// QBLK=64: 4 waves = 2 q-groups (wq) x 2 k-halves (kh). Each wave: 32 q x
// 32 k per 64-k tile => 4 QK^T MFMA32 + 4 PV MFMA32, softmax in registers
// (cvt_pk + permlane32_swap, layout verified in round 4). k-halves combined
// once at the end via swizzled LDS exchange (O partials + denominators).
// Counted-vmcnt pipeline: per wave per iter DMAs = [K,K,V,V]; steady-state
// wait = vmcnt(2) (K 1-iter slack, V 2-iter); lgkmcnt(0) before each raw
// s_barrier keeps cross-wave read-vs-DMA-overwrite ordering.
// Grid 32x32 = 1024 blocks; LDS = 2*8K (K dbuf) + 3*8K (V tri) = 40960 B
// = exactly 4 blocks/CU; VGPR capped 128 => 16 waves/CU (2x round 4).
__global__ __launch_bounds__(256, 4) void attn_kernel(
    const u16* __restrict__ qg, const u16* __restrict__ kg,
    const u16* __restrict__ vtg, u16* __restrict__ ctx) {
  __shared__ __align__(16) u16 KB[2][64 * 64];
  __shared__ __align__(16) u16 VB[3][64 * 64];

  const int bh = blockIdx.x;  // b*16 + h
  const int q0 = blockIdx.y * 64;
  const int t = threadIdx.x;
  const int wid = t >> 6, l = t & 63;
  const int col = l & 31, half = l >> 5;
  const int wq = wid & 1;   // q-group within block
  const int kh = wid >> 1;  // k-half within tile
  const size_t base = (size_t)bh * SDIM * HD;

  const int qw0 = q0 + 32 * wq;  // wave's first q row
  const int qi = qw0 + col;      // this lane's q row

  // Q B-fragments (32x32x16): lane holds Q[q=col][d = 16*f + 8*half + e]
  bf16x8 bq[4];
  {
    const u16* qp = qg + base + (size_t)qi * HD + half * 8;
#pragma unroll
    for (int f = 0; f < 4; f++) bq[f] = *(const bf16x8*)(qp + f * 16);
  }
  // force Q-load completion before async stages are issued
  asm volatile("" : "+v"(bq[0]), "+v"(bq[1]), "+v"(bq[2]), "+v"(bq[3]));

  // staging: each wave stages 16 rows (2 asyncs of 8) of K and of V per tile
  const int sr = l >> 3;            // 0..7
  const int g = (l & 7) ^ sr;       // chunk swizzle; (16w+sr)&7 == (16w+8+sr)&7 == sr
  const u16* kpt = kg + base + (size_t)(16 * wid + sr) * HD + g * 8;
  const u16* vpt = vtg + base + (size_t)(16 * wid + sr) * SDIM + g * 8;

  auto stageK = [&](int kt, int buf) {
    char* d = (char*)KB[buf] + wid * 2048;
    async_lds16(kpt + (size_t)(kt * 64) * HD, d);
    async_lds16(kpt + (size_t)(kt * 64 + 8) * HD, d + 1024);
  };
  auto stageV = [&](int kt, int buf) {
    char* d = (char*)VB[buf] + wid * 2048;
    async_lds16(vpt + kt * 64, d);
    async_lds16(vpt + (size_t)8 * SDIM + kt * 64, d + 1024);
  };

  // QK^T: A = K rows (kr = 32*kh + col), B = Q. D[k][q]; 4 MFMAs over d.
  auto qkt = [&](const u16* Kt, f32x16& sco) {
    const int kr = 32 * kh + col;
    const int r7 = kr & 7;
#pragma unroll
    for (int f = 0; f < 4; f++) {
      int phys = (2 * f + half) ^ r7;
      bf16x8 kf = *(const bf16x8*)&Kt[kr * 64 + phys * 8];
      sco = MFMA32(kf, bq[f], sco);
    }
  };

  float ps0 = 0.f, ps1 = 0.f, ps2 = 0.f, ps3 = 0.f;
  f32x16 oacc[2] = {};

  // softmax: 16 scores/lane, k = kt*64 + 32*kh + (r&3) + 8*(r>>2) + 4*half
  auto smax = [&](int kt, f32x16& cur, bool band, u32 (&w)[8]) {
    float p[16];
#pragma unroll
    for (int r = 0; r < 16; r++) {
      float v = cur[r];
      if (band) {
        int j = kt * 64 + 32 * kh + (r & 3) + 8 * (r >> 2) + 4 * half;
        if (j <= qi && j + 16 >= qi) v = -1.0e30f;
      }
      p[r] = __builtin_exp2f(v);
    }
#pragma unroll
    for (int r = 0; r < 16; r += 4) {
      ps0 += p[r]; ps1 += p[r + 1]; ps2 += p[r + 2]; ps3 += p[r + 3];
    }
#pragma unroll
    for (int j = 0; j < 8; j++)
      asm("v_cvt_pk_bf16_f32 %0, %1, %2"
          : "=v"(w[j]) : "v"(p[2 * j]), "v"(p[2 * j + 1]));
  };

  // PV: pa built by permlane32_swap (verified layout, round 4); ks = 2*kh+b2
  auto pv = [&](const u16* Vt, u32 (&w)[8]) {
#pragma unroll
    for (int b2 = 0; b2 < 2; b2++) {
      u32 x0 = w[4 * b2 + 0], x1 = w[4 * b2 + 1];
      u32 y0 = w[4 * b2 + 2], y1 = w[4 * b2 + 3];
      asm("v_permlane32_swap_b32 %0, %1" : "+v"(x0), "+v"(y0));
      asm("v_permlane32_swap_b32 %0, %1" : "+v"(x1), "+v"(y1));
      uint4 pw;
      pw.x = x0; pw.y = x1; pw.z = y0; pw.w = y1;
      bf16x8 pa = __builtin_bit_cast(bf16x8, pw);
      int ks = 2 * kh + b2;
#pragma unroll
      for (int dt = 0; dt < 2; dt++) {
        int vr = 32 * dt + col;
        int phys = (2 * ks + half) ^ (vr & 7);
        bf16x8 vf = *(const bf16x8*)&Vt[vr * 64 + phys * 8];
        oacc[dt] = MFMA32(vf, pa, oacc[dt]);
      }
    }
  };

  const int NT = SDIM / 64;  // 32
  int vcur = 0, vstg = 2;

  // body(t): wait vmcnt(2) [drains V(t),K(t+1); leaves V(t+1)]; barrier;
  // stage K(t+2),V(t+2); QK^T(t+1) [MFMA bg]; smax(t); PV(t).
  auto body = [&](int kt, f32x16& cur, f32x16& nxt) {
    if (kt < NT - 1)
      asm volatile("s_waitcnt vmcnt(2) lgkmcnt(0)" ::: "memory");
    else
      asm volatile("s_waitcnt vmcnt(0) lgkmcnt(0)" ::: "memory");
    __builtin_amdgcn_s_barrier();
    __builtin_amdgcn_sched_barrier(0);
    if (kt + 2 < NT) {
      stageK(kt + 2, kt & 1);
      stageV(kt + 2, vstg);
    }
    if (kt + 1 < NT) {
      nxt = (f32x16){};
      __builtin_amdgcn_s_setprio(1);
      qkt(KB[(kt + 1) & 1], nxt);
      __builtin_amdgcn_s_setprio(0);
    }
    u32 w[8];
    bool band = (kt * 64 + 32 * kh <= qw0 + 31) &&
                (kt * 64 + 32 * kh + 31 >= qw0 - 16);
    smax(kt, cur, band, w);
    __builtin_amdgcn_s_setprio(1);
    pv(VB[vcur], w);
    __builtin_amdgcn_s_setprio(0);
    vcur = (vcur == 2) ? 0 : vcur + 1;
    vstg = (vstg == 2) ? 0 : vstg + 1;
  };

  f32x16 scA = {}, scB = {};
  // prologue: queue [K0,K0,V0,V0,K1,K1,V1,V1]; drain K0 -> qkt(0)
  stageK(0, 0);
  stageV(0, 0);
  stageK(1, 1);
  stageV(1, 1);
  asm volatile("s_waitcnt vmcnt(6)" ::: "memory");
  __builtin_amdgcn_s_barrier();
  __builtin_amdgcn_sched_barrier(0);
  qkt(KB[0], scA);

#pragma unroll 1
  for (int kt = 0; kt < NT; kt += 2) {
    body(kt, scA, scB);
    body(kt + 1, scB, scA);
  }

  // ---- combine k-halves (flash split-k, exp2 max-free => plain sums) ----
  float pst = (ps0 + ps1) + (ps2 + ps3);
  pst += __shfl_xor(pst, 32, 64);  // lanes l, l^32 hold disjoint k subsets
  __syncthreads();                 // all PV reads done; VB reusable
  char* EXO = (char*)VB;           // 2 x 8192 B, chunk-swizzled
  float* EXP = (float*)((char*)VB + 16384);  // 2 x 32 floats
  if (kh == 1) {
#pragma unroll
    for (int c = 0; c < 8; c++) {
      f32x4 part;
#pragma unroll
      for (int m = 0; m < 4; m++) part[m] = oacc[c >> 2][4 * (c & 3) + m];
      *(f32x4*)(EXO + wq * 8192 + l * 128 + ((c ^ (l & 7)) << 4)) = part;
    }
    if (l < 32) EXP[wq * 32 + l] = pst;
  }
  __syncthreads();
  if (kh == 0) {
    float linv = 1.0f / (pst + EXP[wq * 32 + col]);
#pragma unroll
    for (int c = 0; c < 8; c++) {
      f32x4 part = *(const f32x4*)(EXO + wq * 8192 + l * 128 + ((c ^ (l & 7)) << 4));
#pragma unroll
      for (int m = 0; m < 4; m++) oacc[c >> 2][4 * (c & 3) + m] += part[m];
    }
    // epilogue: lane holds O^T[d][q=qi], d = 32*dt + 8*a + 4*half + (0..3)
    const int b = bh >> 4, h = bh & 15;
    u16* cbase = ctx + ((size_t)(b * SDIM + qi)) * EDIM + h * HD;
#pragma unroll
    for (int dt = 0; dt < 2; dt++)
#pragma unroll
      for (int a = 0; a < 4; a++) {
        float v0 = oacc[dt][4 * a + 0] * linv, v1 = oacc[dt][4 * a + 1] * linv;
        float v2 = oacc[dt][4 * a + 2] * linv, v3 = oacc[dt][4 * a + 3] * linv;
        u32 w0, w1;
        asm("v_cvt_pk_bf16_f32 %0, %1, %2" : "=v"(w0) : "v"(v0), "v"(v1));
        asm("v_cvt_pk_bf16_f32 %0, %1, %2" : "=v"(w1) : "v"(v2), "v"(v3));
        uint2 st;
        st.x = w0;
        st.y = w1;
        *(uint2*)(cbase + 32 * dt + 8 * a + 4 * half) = st;
      }
  }
}

// ===================== GEMM2: output projection (128x128 tile, BK=64) ======
__global__ __launch_bounds__(256) void gemm_out_kernel(
    const u16* __restrict__ A, const u16* __restrict__ W,
    const float* __restrict__ bias, float* __restrict__ out) {
  __shared__ __align__(16) u16 As[128 * 64];
  __shared__ __align__(16) u16 Bs[128 * 64];
  const int m0 = blockIdx.x * 128, n0 = blockIdx.y * 128;
  const int t = threadIdx.x;
  const int l = t & 63;
  const int quad = l >> 4, col = l & 15;
  const int wid = t >> 6;
  const int mh = wid & 1, nh = wid >> 1;
  const int wofs = (t & 192) << 4;
  f32x4 acc[4][4] = {};
  const u16* Ab = A + (size_t)m0 * EDIM;
  const u16* Bb = W + (size_t)n0 * EDIM;
  char* AsB = (char*)As;
  char* BsB = (char*)Bs;

  for (int k0 = 0; k0 < EDIM; k0 += 64) {
    __syncthreads();
#pragma unroll
    for (int p = 0; p < 4; p++) {
      int idx = p * 256 + t;
      int row = idx >> 3;
      int gch = (idx & 7) ^ (row & 7);
      async_lds16(Ab + (size_t)row * EDIM + k0 + gch * 8, AsB + p * 4096 + wofs);
      async_lds16(Bb + (size_t)row * EDIM + k0 + gch * 8, BsB + p * 4096 + wofs);
    }
    __syncthreads();
#pragma unroll
    for (int kk = 0; kk < 2; kk++) {
      bf16x8 af[4], bfr[4];
#pragma unroll
      for (int i = 0; i < 4; i++) {
        int ra = 64 * mh + 16 * i + col;
        af[i] = *(const bf16x8*)&As[ra * 64 + (((kk * 4 + quad) ^ (ra & 7)) * 8)];
        int rb = 64 * nh + 16 * i + col;
        bfr[i] = *(const bf16x8*)&Bs[rb * 64 + (((kk * 4 + quad) ^ (rb & 7)) * 8)];
      }
#pragma unroll
      for (int i = 0; i < 4; i++)
#pragma unroll
        for (int j = 0; j < 4; j++)
          acc[i][j] = MFMA16(af[i], bfr[j], acc[i][j]);
    }
  }

#pragma unroll
  for (int i = 0; i < 4; i++)
#pragma unroll
    for (int j = 0; j < 4; j++)
#pragma unroll
      for (int r = 0; r < 4; r++) {
        int m = m0 + 64 * mh + 16 * i + quad * 4 + r;
        int n = n0 + 64 * nh + 16 * j + col;
        out[(size_t)m * EDIM + n] = acc[i][j][r] + bias[n];
      }
}

extern "C" void kernel_launch(void* const* d_in, const int* in_sizes, int n_in,
                              void* d_out, int out_size, void* d_ws,
                              size_t ws_size, hipStream_t stream) {
  const float* x = (const float*)d_in[0];
  const float* in_w = (const float*)d_in[2];
  const float* in_b = (const float*)d_in[3];
  const float* out_w = (const float*)d_in[4];
  const float* out_b = (const float*)d_in[5];
  float* out = (float*)d_out;

  char* ws = (char*)d_ws;
  u16* Xb  = (u16*)ws;                           // 8 MB (reused as ctx)
  u16* ctx = (u16*)ws;                           // alias of Xb
  u16* qb  = (u16*)(ws + (size_t)( 8 << 20));    // 8 MB (pre-scaled q)
  u16* kb  = (u16*)(ws + (size_t)(16 << 20));    // 8 MB
  u16* vtb = (u16*)(ws + (size_t)(24 << 20));    // 8 MB (transposed V)
  u16* Wib = (u16*)(ws + (size_t)(32 << 20));    // 6 MB
  u16* Wob = (u16*)(ws + (size_t)(38 << 20));    // 2 MB

  const int nX = MDIM * EDIM;
  const int nWi = 3 * EDIM * EDIM;
  const int nWo = EDIM * EDIM;
  cvt3_kernel<<<(nX + nWi + nWo) / 8 / 256, 256, 0, stream>>>(
      x, Xb, nX, in_w, Wib, nWi, out_w, Wob, nWo);

  gemm_qkv_kernel<<<dim3(MDIM / 128, 3 * EDIM / 128), 256, 0, stream>>>(
      Xb, Wib, in_b, qb, kb, vtb);
  attn_kernel<<<dim3(BDIM * HDIM, SDIM / 64), 256, 0, stream>>>(qb, kb, vtb, ctx);
  gemm_out_kernel<<<dim3(MDIM / 128, EDIM / 128), 256, 0, stream>>>(
      ctx, Wob, out_b, out);
}

// Round 6
// 225.096 us; speedup vs baseline: 1.0766x; 1.0766x over previous
//
#include <hip/hip_runtime.h>

typedef __attribute__((ext_vector_type(8))) __bf16 bf16x8;
typedef __attribute__((ext_vector_type(4))) float f32x4;
typedef __attribute__((ext_vector_type(16))) float f32x16;
typedef unsigned short u16;
typedef unsigned int u32;

#define MFMA16(a, b, c) __builtin_amdgcn_mfma_f32_16x16x32_bf16((a), (b), (c), 0, 0, 0)
#define MFMA32(a, b, c) __builtin_amdgcn_mfma_f32_32x32x16_bf16((a), (b), (c), 0, 0, 0)

__device__ __forceinline__ u16 f2bf(float f) {
  return (u16)((__float_as_uint(f) + 0x8000u) >> 16);
}

// dims
#define BDIM 2
#define SDIM 2048
#define EDIM 1024
#define HDIM 16
#define HD 64
#define MDIM (BDIM * SDIM)  // 4096

// q pre-scale: 0.125 * log2(e), folded into q at the QKV-GEMM epilogue
#define SC_C1 0.1803368801111355f

typedef __attribute__((address_space(3))) void lds_void;
typedef __attribute__((address_space(1))) void g_void;

__device__ __forceinline__ void async_lds16(const void* g, void* lds_byte) {
  __builtin_amdgcn_global_load_lds((const g_void*)g, (lds_void*)lds_byte, 16, 0, 0);
}

// ===================== cvt3: three f32 -> bf16 arrays, one launch ==========
__global__ __launch_bounds__(256) void cvt3_kernel(
    const float* __restrict__ s0, u16* __restrict__ d0, int n0,
    const float* __restrict__ s1, u16* __restrict__ d1, int n1,
    const float* __restrict__ s2, u16* __restrict__ d2, int n2) {
  int i = (blockIdx.x * 256 + threadIdx.x) * 8;
  const float* s;
  u16* d;
  if (i < n0) {
    s = s0 + i; d = d0 + i;
  } else if (i < n0 + n1) {
    s = s1 + (i - n0); d = d1 + (i - n0);
  } else if (i < n0 + n1 + n2) {
    s = s2 + (i - n0 - n1); d = d2 + (i - n0 - n1);
  } else {
    return;
  }
  float4 f0 = *(const float4*)(s);
  float4 f1 = *(const float4*)(s + 4);
  union { uint4 u; u16 h[8]; } o;
  o.h[0] = f2bf(f0.x); o.h[1] = f2bf(f0.y); o.h[2] = f2bf(f0.z); o.h[3] = f2bf(f0.w);
  o.h[4] = f2bf(f1.x); o.h[5] = f2bf(f1.y); o.h[6] = f2bf(f1.z); o.h[7] = f2bf(f1.w);
  *(uint4*)(d) = o.u;
}

// ===================== GEMM1: QKV projection (128x128 tile, BK=64) ====
// out: q bf16 [B][H][S][HD] PRE-SCALED by SC_C1; k bf16 [B][H][S][HD];
//      v bf16 TRANSPOSED [B][H][HD][S]
__global__ __launch_bounds__(256) void gemm_qkv_kernel(
    const u16* __restrict__ X, const u16* __restrict__ W,
    const float* __restrict__ bias, u16* __restrict__ qb,
    u16* __restrict__ kb, u16* __restrict__ vtb) {
  __shared__ __align__(16) u16 As[128 * 64];
  __shared__ __align__(16) u16 Bs[128 * 64];
  const int m0 = blockIdx.x * 128, n0 = blockIdx.y * 128;
  const bool isV = (n0 >= 2 * EDIM);
  const int t = threadIdx.x;
  const int l = t & 63;
  const int quad = l >> 4, col = l & 15;
  const int wid = t >> 6;
  const int mh = wid & 1, nh = wid >> 1;
  const int wofs = (t & 192) << 4;  // wave_id * 1024 bytes
  f32x4 acc[4][4] = {};
  const u16* Ab = X + (size_t)m0 * EDIM;
  const u16* Bb = W + (size_t)n0 * EDIM;
  char* AsB = (char*)As;
  char* BsB = (char*)Bs;

  for (int k0 = 0; k0 < EDIM; k0 += 64) {
    __syncthreads();
#pragma unroll
    for (int p = 0; p < 4; p++) {
      int idx = p * 256 + t;       // 0..1023
      int row = idx >> 3;          // 0..127
      int gch = (idx & 7) ^ (row & 7);
      async_lds16(Ab + (size_t)row * EDIM + k0 + gch * 8, AsB + p * 4096 + wofs);
      async_lds16(Bb + (size_t)row * EDIM + k0 + gch * 8, BsB + p * 4096 + wofs);
    }
    __syncthreads();
#pragma unroll
    for (int kk = 0; kk < 2; kk++) {
      bf16x8 af[4], bfr[4];
#pragma unroll
      for (int i = 0; i < 4; i++) {
        int ra = 64 * mh + 16 * i + col;
        af[i] = *(const bf16x8*)&As[ra * 64 + (((kk * 4 + quad) ^ (ra & 7)) * 8)];
        int rb = 64 * nh + 16 * i + col;
        bfr[i] = *(const bf16x8*)&Bs[rb * 64 + (((kk * 4 + quad) ^ (rb & 7)) * 8)];
      }
      if (isV) {
#pragma unroll
        for (int i = 0; i < 4; i++)
#pragma unroll
          for (int j = 0; j < 4; j++)
            acc[i][j] = MFMA16(bfr[i], af[j], acc[i][j]);  // rows = W features
      } else {
#pragma unroll
        for (int i = 0; i < 4; i++)
#pragma unroll
          for (int j = 0; j < 4; j++)
            acc[i][j] = MFMA16(af[i], bfr[j], acc[i][j]);  // rows = tokens
      }
    }
  }

  if (isV) {
#pragma unroll
    for (int i = 0; i < 4; i++)
#pragma unroll
      for (int j = 0; j < 4; j++)
#pragma unroll
        for (int r = 0; r < 4; r++) {
          int n = n0 + 64 * nh + 16 * i + quad * 4 + r;  // feature (2048..3071)
          int m = m0 + 64 * mh + 16 * j + col;           // token
          float val = acc[i][j][r] + bias[n];
          int e = n & 1023;
          int hh = e >> 6, d = e & 63;
          int bb = m >> 11, s = m & 2047;
          vtb[(((size_t)(bb * HDIM + hh)) * HD + d) * SDIM + s] = f2bf(val);
        }
  } else {
    const float qscale = (n0 < EDIM) ? SC_C1 : 1.0f;  // block-uniform
#pragma unroll
    for (int i = 0; i < 4; i++)
#pragma unroll
      for (int j = 0; j < 4; j++)
#pragma unroll
        for (int r = 0; r < 4; r++) {
          int m = m0 + 64 * mh + 16 * i + quad * 4 + r;
          int n = n0 + 64 * nh + 16 * j + col;
          float val = (acc[i][j][r] + bias[n]) * qscale;
          int which = n >> 10, e = n & 1023;
          int hh = e >> 6, d = e & 63;
          int bb = m >> 11, s = m & 2047;
          u16* dst = (which == 0) ? qb : kb;
          dst[(((size_t)(bb * HDIM + hh)) * SDIM + s) * HD + d] = f2bf(val);
        }
  }
}

// ===================== Attention: 2 tiles per barrier, reg softmax ========
// Empirical finding (rounds 0/3/4/5): wall per barrier-iteration is a fixed
// ~2.6 us regardless of inner structure (DMA-drain + barrier convoy floor).
// => halve the number of barrier regions: process tiles (a,b)=(2s,2s+1) per
// region. K/V quad-buffered (buf = tile&3). Region: barrier -> stage
// (a+2,b+2) [8 DMAs, one-full-region slack] -> qkt(a) -> qkt(b)||smax(a)
// -> pv(a)||smax(b) -> pv(b). Compute bricks are round-4 verbatim
// (32x32 swapped QK^T, cvt_pk+permlane32_swap in-reg softmax, V^T PV).
// Grid 32x16=512 blocks; LDS = 8 x 8K = 65536 B -> 2 blocks/CU.
__global__ __launch_bounds__(256) void attn_kernel(
    const u16* __restrict__ qg, const u16* __restrict__ kg,
    const u16* __restrict__ vtg, u16* __restrict__ ctx) {
  __shared__ __align__(16) u16 KB[4][64 * 64];
  __shared__ __align__(16) u16 VB[4][64 * 64];

  const int bh = blockIdx.x;  // b*16 + h
  const int q0 = blockIdx.y * 128;
  const int t = threadIdx.x;
  const int wid = t >> 6, l = t & 63;
  const int col = l & 31, half = l >> 5;
  const size_t base = (size_t)bh * SDIM * HD;

  const int qw0 = q0 + 32 * wid;   // wave's first q row
  const int qi = qw0 + col;        // this lane's q row

  // Q B-fragments (32x32x16): lane holds Q[q=col][d = 16*f + 8*half + e]
  bf16x8 bq[4];
  {
    const u16* qp = qg + base + (size_t)qi * HD + half * 8;
#pragma unroll
    for (int f = 0; f < 4; f++) bq[f] = *(const bf16x8*)(qp + f * 16);
  }
  asm volatile("" : "+v"(bq[0]), "+v"(bq[1]), "+v"(bq[2]), "+v"(bq[3]));

  // staging: row = (t>>3), chunk g = (t&7)^(row&7)  (verified r0-r5)
  const int srow = t >> 3;
  const int g = (t & 7) ^ (srow & 7);
  const u16* kptr = kg + base + (size_t)srow * HD + g * 8;
  const u16* vptr = vtg + base + (size_t)srow * SDIM + g * 8;
  const int wofs = (t & 192) << 4;

  auto stageK = [&](int kt, int buf) {
    char* d = (char*)KB[buf] + wofs;
    async_lds16(kptr + (size_t)(kt * 64) * HD, d);
    async_lds16(kptr + (size_t)(kt * 64 + 32) * HD, d + 4096);
  };
  auto stageV = [&](int kt, int buf) {
    char* d = (char*)VB[buf] + wofs;
    async_lds16(vptr + kt * 64, d);
    async_lds16(vptr + (size_t)32 * SDIM + kt * 64, d + 4096);
  };

  // QK^T(tile): for k-subtile s (32 k) and d-frag f (16 d):
  // A = K[kr = 32s+col][d = 16f + 8*half + e]  (chunk 2f+half, XOR row swz)
  auto qkt = [&](const u16* Kt, f32x16 (&sco)[2]) {
#pragma unroll
    for (int s = 0; s < 2; s++)
#pragma unroll
      for (int f = 0; f < 4; f++) {
        int kr = 32 * s + col;
        int phys = (2 * f + half) ^ (kr & 7);
        bf16x8 kf = *(const bf16x8*)&Kt[kr * 64 + phys * 8];
        sco[s] = MFMA32(kf, bq[f], sco[s]);
      }
  };

  float ps0 = 0.f, ps1 = 0.f, ps2 = 0.f, ps3 = 0.f;
  f32x16 oacc[2] = {};

  // softmax(t): 32 scores per lane (q=qi), round-4 verbatim.
  auto smax = [&](int kt, f32x16 (&cur)[2], bool band, u32 (&w)[2][8]) {
#pragma unroll
    for (int s = 0; s < 2; s++) {
      float p[16];
#pragma unroll
      for (int r = 0; r < 16; r++) {
        float v = cur[s][r];
        if (band) {
          int j = kt * 64 + 32 * s + (r & 3) + 8 * (r >> 2) + 4 * half;
          if (j <= qi && j + 16 >= qi) v = -1.0e30f;
        }
        p[r] = __builtin_exp2f(v);
      }
#pragma unroll
      for (int r = 0; r < 16; r++) {
        if ((r & 3) == 0) ps0 += p[r];
        else if ((r & 3) == 1) ps1 += p[r];
        else if ((r & 3) == 2) ps2 += p[r];
        else ps3 += p[r];
      }
#pragma unroll
      for (int j = 0; j < 8; j++) {
        u32 wv;
        asm("v_cvt_pk_bf16_f32 %0, %1, %2" : "=v"(wv) : "v"(p[2 * j]), "v"(p[2 * j + 1]));
        w[s][j] = wv;
      }
    }
  };

  // PV(t): round-4 verbatim (permlane32_swap-built B-fragments).
  auto pv = [&](const u16* Vt, u32 (&w)[2][8]) {
#pragma unroll
    for (int s = 0; s < 2; s++)
#pragma unroll
      for (int b2 = 0; b2 < 2; b2++) {
        u32 x0 = w[s][4 * b2 + 0], x1 = w[s][4 * b2 + 1];
        u32 y0 = w[s][4 * b2 + 2], y1 = w[s][4 * b2 + 3];
        asm("v_permlane32_swap_b32 %0, %1" : "+v"(x0), "+v"(y0));
        asm("v_permlane32_swap_b32 %0, %1" : "+v"(x1), "+v"(y1));
        uint4 pw;
        pw.x = x0; pw.y = x1; pw.z = y0; pw.w = y1;
        bf16x8 pa = __builtin_bit_cast(bf16x8, pw);
        int ks = 2 * s + b2;
#pragma unroll
        for (int dt = 0; dt < 2; dt++) {
          int vr = 32 * dt + col;
          int phys = (2 * ks + half) ^ (vr & 7);
          bf16x8 vf = *(const bf16x8*)&Vt[vr * 64 + phys * 8];
          oacc[dt] = MFMA32(vf, pa, oacc[dt]);
        }
      }
  };

  const int NT = SDIM / 64;  // 32 tiles -> 16 barrier regions

  // prologue: tiles 0,1 staged (drained at first barrier)
  stageK(0, 0);
  stageV(0, 0);
  stageK(1, 1);
  stageV(1, 1);

  f32x16 scA[2], scB[2];
#pragma unroll 1
  for (int s = 0; s < NT / 2; s++) {
    const int a = 2 * s, b = a + 1;
    __syncthreads();  // tiles a,b fully in LDS; bufs (a+2)&3,(b+2)&3 reusable
    if (s < NT / 2 - 1) {
      stageK(a + 2, (a + 2) & 3);
      stageV(a + 2, (a + 2) & 3);
      stageK(b + 2, (b + 2) & 3);
      stageV(b + 2, (b + 2) & 3);
    }
    scA[0] = (f32x16){};
    scA[1] = (f32x16){};
    qkt(KB[a & 3], scA);
    scB[0] = (f32x16){};
    scB[1] = (f32x16){};
    qkt(KB[b & 3], scB);  // MFMA — scheduler overlaps with smax(a) VALU below
    u32 wA[2][8], wB[2][8];
    const bool bandA = (a * 64 <= qw0 + 31) && (a * 64 + 63 >= qw0 - 16);
    smax(a, scA, bandA, wA);
    pv(VB[a & 3], wA);    // MFMA — overlaps smax(b) VALU below
    const bool bandB = (b * 64 <= qw0 + 31) && (b * 64 + 63 >= qw0 - 16);
    smax(b, scB, bandB, wB);
    pv(VB[b & 3], wB);
  }

  // l(q) = psum(lane) + psum(lane^32)  (halves hold disjoint k subsets)
  float psum = (ps0 + ps1) + (ps2 + ps3);
  psum += __shfl_xor(psum, 32, 64);
  float linv = 1.0f / psum;

  // epilogue: lane holds O^T[d][q=qi]: d = 32*dt + 8*a + 4*half + (0..3)
  const int b = bh >> 4, h = bh & 15;
  u16* cbase = ctx + ((size_t)(b * SDIM + qi)) * EDIM + h * HD;
#pragma unroll
  for (int dt = 0; dt < 2; dt++)
#pragma unroll
    for (int a = 0; a < 4; a++) {
      float v0 = oacc[dt][4 * a + 0] * linv, v1 = oacc[dt][4 * a + 1] * linv;
      float v2 = oacc[dt][4 * a + 2] * linv, v3 = oacc[dt][4 * a + 3] * linv;
      u32 w0, w1;
      asm("v_cvt_pk_bf16_f32 %0, %1, %2" : "=v"(w0) : "v"(v0), "v"(v1));
      asm("v_cvt_pk_bf16_f32 %0, %1, %2" : "=v"(w1) : "v"(v2), "v"(v3));
      uint2 st;
      st.x = w0; st.y = w1;
      *(uint2*)(cbase + 32 * dt + 8 * a + 4 * half) = st;
    }
}

// ===================== GEMM2: output projection (128x128 tile, BK=64) ======
__global__ __launch_bounds__(256) void gemm_out_kernel(
    const u16* __restrict__ A, const u16* __restrict__ W,
    const float* __restrict__ bias, float* __restrict__ out) {
  __shared__ __align__(16) u16 As[128 * 64];
  __shared__ __align__(16) u16 Bs[128 * 64];
  const int m0 = blockIdx.x * 128, n0 = blockIdx.y * 128;
  const int t = threadIdx.x;
  const int l = t & 63;
  const int quad = l >> 4, col = l & 15;
  const int wid = t >> 6;
  const int mh = wid & 1, nh = wid >> 1;
  const int wofs = (t & 192) << 4;
  f32x4 acc[4][4] = {};
  const u16* Ab = A + (size_t)m0 * EDIM;
  const u16* Bb = W + (size_t)n0 * EDIM;
  char* AsB = (char*)As;
  char* BsB = (char*)Bs;

  for (int k0 = 0; k0 < EDIM; k0 += 64) {
    __syncthreads();
#pragma unroll
    for (int p = 0; p < 4; p++) {
      int idx = p * 256 + t;
      int row = idx >> 3;
      int gch = (idx & 7) ^ (row & 7);
      async_lds16(Ab + (size_t)row * EDIM + k0 + gch * 8, AsB + p * 4096 + wofs);
      async_lds16(Bb + (size_t)row * EDIM + k0 + gch * 8, BsB + p * 4096 + wofs);
    }
    __syncthreads();
#pragma unroll
    for (int kk = 0; kk < 2; kk++) {
      bf16x8 af[4], bfr[4];
#pragma unroll
      for (int i = 0; i < 4; i++) {
        int ra = 64 * mh + 16 * i + col;
        af[i] = *(const bf16x8*)&As[ra * 64 + (((kk * 4 + quad) ^ (ra & 7)) * 8)];
        int rb = 64 * nh + 16 * i + col;
        bfr[i] = *(const bf16x8*)&Bs[rb * 64 + (((kk * 4 + quad) ^ (rb & 7)) * 8)];
      }
#pragma unroll
      for (int i = 0; i < 4; i++)
#pragma unroll
        for (int j = 0; j < 4; j++)
          acc[i][j] = MFMA16(af[i], bfr[j], acc[i][j]);
    }
  }

#pragma unroll
  for (int i = 0; i < 4; i++)
#pragma unroll
    for (int j = 0; j < 4; j++)
#pragma unroll
      for (int r = 0; r < 4; r++) {
        int m = m0 + 64 * mh + 16 * i + quad * 4 + r;
        int n = n0 + 64 * nh + 16 * j + col;
        out[(size_t)m * EDIM + n] = acc[i][j][r] + bias[n];
      }
}

extern "C" void kernel_launch(void* const* d_in, const int* in_sizes, int n_in,
                              void* d_out, int out_size, void* d_ws,
                              size_t ws_size, hipStream_t stream) {
  const float* x = (const float*)d_in[0];
  const float* in_w = (const float*)d_in[2];
  const float* in_b = (const float*)d_in[3];
  const float* out_w = (const float*)d_in[4];
  const float* out_b = (const float*)d_in[5];
  float* out = (float*)d_out;

  char* ws = (char*)d_ws;
  u16* Xb  = (u16*)ws;                           // 8 MB (reused as ctx)
  u16* ctx = (u16*)ws;                           // alias of Xb
  u16* qb  = (u16*)(ws + (size_t)( 8 << 20));    // 8 MB (pre-scaled q)
  u16* kb  = (u16*)(ws + (size_t)(16 << 20));    // 8 MB
  u16* vtb = (u16*)(ws + (size_t)(24 << 20));    // 8 MB (transposed V)
  u16* Wib = (u16*)(ws + (size_t)(32 << 20));    // 6 MB
  u16* Wob = (u16*)(ws + (size_t)(38 << 20));    // 2 MB

  const int nX = MDIM * EDIM;
  const int nWi = 3 * EDIM * EDIM;
  const int nWo = EDIM * EDIM;
  cvt3_kernel<<<(nX + nWi + nWo) / 8 / 256, 256, 0, stream>>>(
      x, Xb, nX, in_w, Wib, nWi, out_w, Wob, nWo);

  gemm_qkv_kernel<<<dim3(MDIM / 128, 3 * EDIM / 128), 256, 0, stream>>>(
      Xb, Wib, in_b, qb, kb, vtb);
  attn_kernel<<<dim3(BDIM * HDIM, SDIM / 128), 256, 0, stream>>>(qb, kb, vtb, ctx);
  gemm_out_kernel<<<dim3(MDIM / 128, EDIM / 128), 256, 0, stream>>>(
      ctx, Wob, out_b, out);
}